// Round 6
// baseline (2797.545 us; speedup 1.0000x reference)
//
#include <hip/hip_runtime.h>
#include <stdint.h>

// RNNTextClassifier: B=64, S=512, E=H=512, NCLS=8
// Round 9: per-wave full-K restructure. Each block = 256 thr / 4 waves;
// wave w owns a 16-col n-slice (cols c*64+w*16..) with FULL K=512 in VGPR
// weights (wih[16], whhh[16], whhl[16] = 192 VGPRs/thread). Removes the
// kq-split cross-wave reduction: no s_part, no B3 (3 barriers -> 2),
// finals per-lane from own accumulators, publish fires right after the
// wave's own MFMA chain (shortens producer->consumer serial path).
// 4 independent accumulators break the 64-MFMA dependent chain.
// Protocol (proven R3/R6/R8): tagged-data device-scope polls, ring slot=s&3
// tag=s&7, layer0 bp-polls layer1 progress. Self-contained spin loops only.
// ws: hsl 1MB at offset 0 (memset to 0 each launch).

#define BB 64
#define SS 512
#define HH 512

typedef short bf16x8 __attribute__((ext_vector_type(8)));
typedef float f32x4 __attribute__((ext_vector_type(4)));
typedef int i32x4 __attribute__((ext_vector_type(4)));
typedef unsigned int u32;

__device__ __forceinline__ unsigned short f2bf(float f) {
  uint32_t u = __builtin_bit_cast(uint32_t, f);
  u += 0x7FFFu + ((u >> 16) & 1u);
  return (unsigned short)(u >> 16);
}
__device__ __forceinline__ float bf2f(unsigned short h) {
  uint32_t u = ((uint32_t)h) << 16;
  return __builtin_bit_cast(float, u);
}
__device__ __forceinline__ int pack2(unsigned short a, unsigned short b) {
  return (int)(unsigned int)a | ((int)(unsigned int)b << 16);
}
// pack hi halves of two tagged words (a -> low half, b -> high)
__device__ __forceinline__ u32 hipack(u32 a, u32 b) {
  return (a >> 16) | (b & 0xFFFF0000u);
}
// pack lo halves (tag bits stripped)
__device__ __forceinline__ u32 lopack(u32 a, u32 b) {
  return (a & 0xFFF8u) | ((b & 0xFFF8u) << 16);
}
__device__ __forceinline__ bool tag4(i32x4 v, u32 t) {
  u32 m = (((u32)v[0] ^ t) | ((u32)v[1] ^ t) | ((u32)v[2] ^ t) | ((u32)v[3] ^ t)) & 7u;
  return m == 0u;
}
// fast tanh: t = sign(v)*(1-e)/(1+e), e = exp(-2|v|). |err| ~1e-7.
__device__ __forceinline__ float fast_tanh(float v) {
  float a = __builtin_fabsf(v);
  float e = __expf(-2.0f * a);
  float t = (1.0f - e) / (1.0f + e);
  return __builtin_copysignf(t, v);
}

// device-coherent (UC) loads/stores: bypass non-common caches
#define UC_LOAD4(dst, ptr) \
  asm volatile("global_load_dwordx4 %0, %1, off sc0 sc1" : "=v"(dst) : "v"(ptr))
#define UC_LOAD1(dst, ptr) \
  asm volatile("global_load_dword %0, %1, off sc0 sc1" : "=v"(dst) : "v"(ptr))
#define UC_STORE1(ptr, v) \
  asm volatile("global_store_dword %0, %1, off sc0 sc1" ::"v"(ptr), "v"(v) : "memory")

__global__ __launch_bounds__(256, 1) void k_rnn(
    const int* __restrict__ x, const float* __restrict__ emb,
    const float* __restrict__ Wih0, const float* __restrict__ Whh0,
    const float* __restrict__ bih0, const float* __restrict__ bhh0,
    const float* __restrict__ Wih1, const float* __restrict__ Whh1,
    const float* __restrict__ bih1, const float* __restrict__ bhh1,
    u32* __restrict__ hsl) {
  const int tid = threadIdx.x;
  const int bid = blockIdx.x;
  const int layer = bid >> 5;  // 0 or 1
  const int lb = bid & 31;
  const int bg = lb >> 3;  // batch group (16 rows)
  const int c = lb & 7;    // hidden slice (64 dims)
  const int wid = tid >> 6; // wave: n-16-tile within the 64-col slice
  const int lane = tid & 63;
  const int r16 = lane & 15, kg = lane >> 4;

  __shared__ __align__(16) unsigned short s_in0[16 * 512];
  __shared__ __align__(16) unsigned short s_Hhi[16 * 512];
  __shared__ __align__(16) unsigned short s_Hlo[16 * 512];

  const float* Wih = layer ? Wih1 : Wih0;
  const float* Whh = layer ? Whh1 : Whh0;
  const float* bi = layer ? bih1 : bih0;
  const float* bh = layer ? bhh1 : bhh0;

  // ---- one-time: full-K W fragments for this wave's 16-col slice ----
  bf16x8 wih[16], whhh[16], whhl[16];
  {
    const int row = c * 64 + wid * 16 + r16;
#pragma unroll
    for (int kt = 0; kt < 16; ++kt) {
      const int k0 = kt * 32 + kg * 8;
      const float* p = Wih + row * 512 + k0;
      bf16x8 v;
#pragma unroll
      for (int j = 0; j < 8; ++j) v[j] = (short)f2bf(p[j]);
      wih[kt] = v;
      const float* q = Whh + row * 512 + k0;
      bf16x8 vh, vl;
#pragma unroll
      for (int j = 0; j < 8; ++j) {
        float f = q[j];
        unsigned short h = f2bf(f);
        vh[j] = (short)h;
        vl[j] = (short)f2bf(f - bf2f(h));
      }
      whhh[kt] = vh;
      whhl[kt] = vl;
    }
  }
  float bv;
  {
    const int gcol = c * 64 + wid * 16 + r16;
    bv = bi[gcol] + bh[gcol];
  }

  const int r_st = tid >> 4;  // staging row 0..15
  const int ch = tid & 15;    // 32-word chunk of 512

  // prefetch in0 for step 1 (layer0: emb gather t=0): 32 f32 per thread
  float4 pf0, pf1, pf2, pf3, pf4, pf5, pf6, pf7;
  if (layer == 0) {
    int rid = x[(bg * 16 + r_st) * SS + 0];
    const float4* ep = (const float4*)(emb + (size_t)rid * 512 + ch * 32);
    pf0 = ep[0]; pf1 = ep[1]; pf2 = ep[2]; pf3 = ep[3];
    pf4 = ep[4]; pf5 = ep[5]; pf6 = ep[6]; pf7 = ep[7];
  }

  for (int s = 1; s <= SS; ++s) {
    const u32 exp_h = (u32)((s - 1) & 7);
    const u32* ph = hsl +
        (((size_t)layer * 4 + ((s - 1) & 3)) * 64 + bg * 16 + r_st) * 512 + ch * 32;

    // ============ pre-poll phase: h-independent work ============
    if (layer == 0) {
      // stage in0 from prefetched emb f32 (swizzled LDS; chunks ch*4+j)
      i32x4 v0 = {pack2(f2bf(pf0.x), f2bf(pf0.y)), pack2(f2bf(pf0.z), f2bf(pf0.w)),
                  pack2(f2bf(pf1.x), f2bf(pf1.y)), pack2(f2bf(pf1.z), f2bf(pf1.w))};
      i32x4 v1 = {pack2(f2bf(pf2.x), f2bf(pf2.y)), pack2(f2bf(pf2.z), f2bf(pf2.w)),
                  pack2(f2bf(pf3.x), f2bf(pf3.y)), pack2(f2bf(pf3.z), f2bf(pf3.w))};
      i32x4 v2 = {pack2(f2bf(pf4.x), f2bf(pf4.y)), pack2(f2bf(pf4.z), f2bf(pf4.w)),
                  pack2(f2bf(pf5.x), f2bf(pf5.y)), pack2(f2bf(pf5.z), f2bf(pf5.w))};
      i32x4 v3 = {pack2(f2bf(pf6.x), f2bf(pf6.y)), pack2(f2bf(pf6.z), f2bf(pf6.w)),
                  pack2(f2bf(pf7.x), f2bf(pf7.y)), pack2(f2bf(pf7.z), f2bf(pf7.w))};
      *(i32x4*)(s_in0 + r_st * 512 + (((ch * 4 + 0) ^ (r_st & 7)) << 3)) = v0;
      *(i32x4*)(s_in0 + r_st * 512 + (((ch * 4 + 1) ^ (r_st & 7)) << 3)) = v1;
      *(i32x4*)(s_in0 + r_st * 512 + (((ch * 4 + 2) ^ (r_st & 7)) << 3)) = v2;
      *(i32x4*)(s_in0 + r_st * 512 + (((ch * 4 + 3) ^ (r_st & 7)) << 3)) = v3;
      // issue emb prefetch for s+1 (plain cached loads; hide under polls)
      if (s < SS) {
        int rid = x[(bg * 16 + r_st) * SS + s];
        const float4* ep = (const float4*)(emb + (size_t)rid * 512 + ch * 32);
        pf0 = ep[0]; pf1 = ep[1]; pf2 = ep[2]; pf3 = ep[3];
        pf4 = ep[4]; pf5 = ep[5]; pf6 = ep[6]; pf7 = ep[7];
      }
    } else {
      // layer1: poll in0 = out0[s] (self-contained spin, proven shape)
      i32x4 i0 = {0, 0, 0, 0}, i1 = {0, 0, 0, 0}, i2 = {0, 0, 0, 0}, i3 = {0, 0, 0, 0};
      i32x4 i4 = {0, 0, 0, 0}, i5 = {0, 0, 0, 0}, i6 = {0, 0, 0, 0}, i7 = {0, 0, 0, 0};
      const u32 exp_i = (u32)(s & 7);
      const u32* pi =
          hsl + (((size_t)(s & 3)) * 64 + bg * 16 + r_st) * 512 + ch * 32;
      while (true) {
        UC_LOAD4(i0, pi);
        UC_LOAD4(i1, pi + 4);
        UC_LOAD4(i2, pi + 8);
        UC_LOAD4(i3, pi + 12);
        UC_LOAD4(i4, pi + 16);
        UC_LOAD4(i5, pi + 20);
        UC_LOAD4(i6, pi + 24);
        UC_LOAD4(i7, pi + 28);
        asm volatile("s_waitcnt vmcnt(0)"
                     : "+v"(i0), "+v"(i1), "+v"(i2), "+v"(i3), "+v"(i4), "+v"(i5),
                       "+v"(i6), "+v"(i7)::"memory");
        bool ok = tag4(i0, exp_i) && tag4(i1, exp_i) && tag4(i2, exp_i) &&
                  tag4(i3, exp_i) && tag4(i4, exp_i) && tag4(i5, exp_i) &&
                  tag4(i6, exp_i) && tag4(i7, exp_i);
        if (__all(ok)) break;
      }
      // stage in0 (hi halves only) into swizzled LDS
      i32x4 A0 = {(int)hipack(i0[0], i0[1]), (int)hipack(i0[2], i0[3]),
                  (int)hipack(i1[0], i1[1]), (int)hipack(i1[2], i1[3])};
      i32x4 A1 = {(int)hipack(i2[0], i2[1]), (int)hipack(i2[2], i2[3]),
                  (int)hipack(i3[0], i3[1]), (int)hipack(i3[2], i3[3])};
      i32x4 A2 = {(int)hipack(i4[0], i4[1]), (int)hipack(i4[2], i4[3]),
                  (int)hipack(i5[0], i5[1]), (int)hipack(i5[2], i5[3])};
      i32x4 A3 = {(int)hipack(i6[0], i6[1]), (int)hipack(i6[2], i6[3]),
                  (int)hipack(i7[0], i7[1]), (int)hipack(i7[2], i7[3])};
      *(i32x4*)(s_in0 + r_st * 512 + (((ch * 4 + 0) ^ (r_st & 7)) << 3)) = A0;
      *(i32x4*)(s_in0 + r_st * 512 + (((ch * 4 + 1) ^ (r_st & 7)) << 3)) = A1;
      *(i32x4*)(s_in0 + r_st * 512 + (((ch * 4 + 2) ^ (r_st & 7)) << 3)) = A2;
      *(i32x4*)(s_in0 + r_st * 512 + (((ch * 4 + 3) ^ (r_st & 7)) << 3)) = A3;
    }
    __syncthreads();  // B1: s_in0 staged

    // ---- in0 MFMAs: full K, 4 independent acc chains ----
    f32x4 acc0 = {0.f, 0.f, 0.f, 0.f};
    f32x4 acc1 = {0.f, 0.f, 0.f, 0.f};
    f32x4 acc2 = {0.f, 0.f, 0.f, 0.f};
    f32x4 acc3 = {0.f, 0.f, 0.f, 0.f};
#pragma unroll
    for (int kt = 0; kt < 16; ++kt) {
      const int k8 = kt * 4 + kg;
      bf16x8 ain = __builtin_bit_cast(
          bf16x8, *(const i32x4*)(s_in0 + r16 * 512 + ((k8 ^ (r16 & 7)) << 3)));
      if ((kt & 3) == 0) acc0 = __builtin_amdgcn_mfma_f32_16x16x32_bf16(ain, wih[kt], acc0, 0, 0, 0);
      if ((kt & 3) == 1) acc1 = __builtin_amdgcn_mfma_f32_16x16x32_bf16(ain, wih[kt], acc1, 0, 0, 0);
      if ((kt & 3) == 2) acc2 = __builtin_amdgcn_mfma_f32_16x16x32_bf16(ain, wih[kt], acc2, 0, 0, 0);
      if ((kt & 3) == 3) acc3 = __builtin_amdgcn_mfma_f32_16x16x32_bf16(ain, wih[kt], acc3, 0, 0, 0);
    }

    // ============ H poll (self-contained) + stage ============
    if (s > 1) {
      i32x4 h0 = {0, 0, 0, 0}, h1 = {0, 0, 0, 0}, h2 = {0, 0, 0, 0}, h3 = {0, 0, 0, 0};
      i32x4 h4 = {0, 0, 0, 0}, h5 = {0, 0, 0, 0}, h6 = {0, 0, 0, 0}, h7 = {0, 0, 0, 0};
      if (layer == 0) {
        const bool need_bp = (s > 4) && (tid < 8);
        const u32 exp_bp = (u32)((s - 4) & 7);
        const u32* pbp = hsl + ((size_t)(4 + ((s - 4) & 3)) * 64 + bg * 16) * 512 +
                         (tid < 8 ? tid * 64 : 0);
        while (true) {
          u32 bpw = 0;
          UC_LOAD4(h0, ph);
          UC_LOAD4(h1, ph + 4);
          UC_LOAD4(h2, ph + 8);
          UC_LOAD4(h3, ph + 12);
          UC_LOAD4(h4, ph + 16);
          UC_LOAD4(h5, ph + 20);
          UC_LOAD4(h6, ph + 24);
          UC_LOAD4(h7, ph + 28);
          UC_LOAD1(bpw, pbp);
          asm volatile("s_waitcnt vmcnt(0)"
                       : "+v"(h0), "+v"(h1), "+v"(h2), "+v"(h3), "+v"(h4), "+v"(h5),
                         "+v"(h6), "+v"(h7), "+v"(bpw)::"memory");
          bool ok = tag4(h0, exp_h) && tag4(h1, exp_h) && tag4(h2, exp_h) &&
                    tag4(h3, exp_h) && tag4(h4, exp_h) && tag4(h5, exp_h) &&
                    tag4(h6, exp_h) && tag4(h7, exp_h) &&
                    (!need_bp || ((bpw & 7u) == exp_bp));
          if (__all(ok)) break;
        }
      } else {
        while (true) {
          UC_LOAD4(h0, ph);
          UC_LOAD4(h1, ph + 4);
          UC_LOAD4(h2, ph + 8);
          UC_LOAD4(h3, ph + 12);
          UC_LOAD4(h4, ph + 16);
          UC_LOAD4(h5, ph + 20);
          UC_LOAD4(h6, ph + 24);
          UC_LOAD4(h7, ph + 28);
          asm volatile("s_waitcnt vmcnt(0)"
                       : "+v"(h0), "+v"(h1), "+v"(h2), "+v"(h3), "+v"(h4), "+v"(h5),
                         "+v"(h6), "+v"(h7)::"memory");
          bool ok = tag4(h0, exp_h) && tag4(h1, exp_h) && tag4(h2, exp_h) &&
                    tag4(h3, exp_h) && tag4(h4, exp_h) && tag4(h5, exp_h) &&
                    tag4(h6, exp_h) && tag4(h7, exp_h);
          if (__all(ok)) break;
        }
      }
      // stage H hi/lo (deinterleave tagged words; chunks ch*4+j)
      i32x4 A0 = {(int)hipack(h0[0], h0[1]), (int)hipack(h0[2], h0[3]),
                  (int)hipack(h1[0], h1[1]), (int)hipack(h1[2], h1[3])};
      i32x4 A1 = {(int)hipack(h2[0], h2[1]), (int)hipack(h2[2], h2[3]),
                  (int)hipack(h3[0], h3[1]), (int)hipack(h3[2], h3[3])};
      i32x4 A2 = {(int)hipack(h4[0], h4[1]), (int)hipack(h4[2], h4[3]),
                  (int)hipack(h5[0], h5[1]), (int)hipack(h5[2], h5[3])};
      i32x4 A3 = {(int)hipack(h6[0], h6[1]), (int)hipack(h6[2], h6[3]),
                  (int)hipack(h7[0], h7[1]), (int)hipack(h7[2], h7[3])};
      i32x4 B0 = {(int)lopack(h0[0], h0[1]), (int)lopack(h0[2], h0[3]),
                  (int)lopack(h1[0], h1[1]), (int)lopack(h1[2], h1[3])};
      i32x4 B1v = {(int)lopack(h2[0], h2[1]), (int)lopack(h2[2], h2[3]),
                   (int)lopack(h3[0], h3[1]), (int)lopack(h3[2], h3[3])};
      i32x4 B2v = {(int)lopack(h4[0], h4[1]), (int)lopack(h4[2], h4[3]),
                   (int)lopack(h5[0], h5[1]), (int)lopack(h5[2], h5[3])};
      i32x4 B3v = {(int)lopack(h6[0], h6[1]), (int)lopack(h6[2], h6[3]),
                   (int)lopack(h7[0], h7[1]), (int)lopack(h7[2], h7[3])};
      *(i32x4*)(s_Hhi + r_st * 512 + (((ch * 4 + 0) ^ (r_st & 7)) << 3)) = A0;
      *(i32x4*)(s_Hhi + r_st * 512 + (((ch * 4 + 1) ^ (r_st & 7)) << 3)) = A1;
      *(i32x4*)(s_Hhi + r_st * 512 + (((ch * 4 + 2) ^ (r_st & 7)) << 3)) = A2;
      *(i32x4*)(s_Hhi + r_st * 512 + (((ch * 4 + 3) ^ (r_st & 7)) << 3)) = A3;
      *(i32x4*)(s_Hlo + r_st * 512 + (((ch * 4 + 0) ^ (r_st & 7)) << 3)) = B0;
      *(i32x4*)(s_Hlo + r_st * 512 + (((ch * 4 + 1) ^ (r_st & 7)) << 3)) = B1v;
      *(i32x4*)(s_Hlo + r_st * 512 + (((ch * 4 + 2) ^ (r_st & 7)) << 3)) = B2v;
      *(i32x4*)(s_Hlo + r_st * 512 + (((ch * 4 + 3) ^ (r_st & 7)) << 3)) = B3v;
    }
    __syncthreads();  // B2: s_H staged

    // ---- H MFMAs: full K, hi/lo 3-term, 4 independent chains ----
    if (s > 1) {
#pragma unroll
      for (int kt = 0; kt < 16; ++kt) {
        const int k8 = kt * 4 + kg;
        bf16x8 ahi = __builtin_bit_cast(
            bf16x8, *(const i32x4*)(s_Hhi + r16 * 512 + ((k8 ^ (r16 & 7)) << 3)));
        bf16x8 alo = __builtin_bit_cast(
            bf16x8, *(const i32x4*)(s_Hlo + r16 * 512 + ((k8 ^ (r16 & 7)) << 3)));
        if ((kt & 3) == 0) {
          acc0 = __builtin_amdgcn_mfma_f32_16x16x32_bf16(ahi, whhh[kt], acc0, 0, 0, 0);
          acc0 = __builtin_amdgcn_mfma_f32_16x16x32_bf16(ahi, whhl[kt], acc0, 0, 0, 0);
          acc0 = __builtin_amdgcn_mfma_f32_16x16x32_bf16(alo, whhh[kt], acc0, 0, 0, 0);
        }
        if ((kt & 3) == 1) {
          acc1 = __builtin_amdgcn_mfma_f32_16x16x32_bf16(ahi, whhh[kt], acc1, 0, 0, 0);
          acc1 = __builtin_amdgcn_mfma_f32_16x16x32_bf16(ahi, whhl[kt], acc1, 0, 0, 0);
          acc1 = __builtin_amdgcn_mfma_f32_16x16x32_bf16(alo, whhh[kt], acc1, 0, 0, 0);
        }
        if ((kt & 3) == 2) {
          acc2 = __builtin_amdgcn_mfma_f32_16x16x32_bf16(ahi, whhh[kt], acc2, 0, 0, 0);
          acc2 = __builtin_amdgcn_mfma_f32_16x16x32_bf16(ahi, whhl[kt], acc2, 0, 0, 0);
          acc2 = __builtin_amdgcn_mfma_f32_16x16x32_bf16(alo, whhh[kt], acc2, 0, 0, 0);
        }
        if ((kt & 3) == 3) {
          acc3 = __builtin_amdgcn_mfma_f32_16x16x32_bf16(ahi, whhh[kt], acc3, 0, 0, 0);
          acc3 = __builtin_amdgcn_mfma_f32_16x16x32_bf16(ahi, whhl[kt], acc3, 0, 0, 0);
          acc3 = __builtin_amdgcn_mfma_f32_16x16x32_bf16(alo, whhh[kt], acc3, 0, 0, 0);
        }
      }
    }

    // ---- finals per lane: no cross-wave reduce, publish immediately ----
    {
      f32x4 fa = acc0 + acc1 + acc2 + acc3;
      const u32 tag = (u32)(s & 7);
      u32* dst = hsl + (((size_t)layer * 4 + (s & 3)) * 64 + bg * 16 + kg * 4) * 512 +
                 c * 64 + wid * 16 + r16;
#pragma unroll
      for (int j = 0; j < 4; ++j) {
        float t = fast_tanh(fa[j] + bv);
        unsigned short a = f2bf(t);
        unsigned short b = f2bf(t - bf2f(a));
        u32 wv = ((u32)a << 16) | ((u32)b & 0xFFF8u) | tag;
        UC_STORE1(dst + j * 512, wv);
      }
    }
    // no drain, no flag: consumers detect via embedded tags
  }
}

__global__ void k_fc(const u32* __restrict__ h1w, const float* __restrict__ fcW,
                     const float* __restrict__ fcb, float* __restrict__ out) {
  int i = threadIdx.x;  // 512 = 64 batch x 8 classes
  int b = i >> 3, cc = i & 7;
  float acc = fcb[cc];
  const u32* ph = h1w + b * 512;
  const float* pw = fcW + cc * 512;
  for (int k = 0; k < 512; k += 4) {
    int4 w4 = *(const int4*)(ph + k);
    float4 wv = *(const float4*)(pw + k);
    acc += (bf2f((unsigned short)((u32)w4.x >> 16)) +
            bf2f((unsigned short)((u32)w4.x & 0xFFF8u))) * wv.x;
    acc += (bf2f((unsigned short)((u32)w4.y >> 16)) +
            bf2f((unsigned short)((u32)w4.y & 0xFFF8u))) * wv.y;
    acc += (bf2f((unsigned short)((u32)w4.z >> 16)) +
            bf2f((unsigned short)((u32)w4.z & 0xFFF8u))) * wv.z;
    acc += (bf2f((unsigned short)((u32)w4.w >> 16)) +
            bf2f((unsigned short)((u32)w4.w & 0xFFF8u))) * wv.w;
  }
  out[b * 8 + cc] = acc;
}

extern "C" void kernel_launch(void* const* d_in, const int* in_sizes, int n_in,
                              void* d_out, int out_size, void* d_ws, size_t ws_size,
                              hipStream_t stream) {
  const int* x = (const int*)d_in[0];
  const float* emb = (const float*)d_in[1];
  const float* Wih0 = (const float*)d_in[2];
  const float* Whh0 = (const float*)d_in[3];
  const float* bih0 = (const float*)d_in[4];
  const float* bhh0 = (const float*)d_in[5];
  const float* Wih1 = (const float*)d_in[6];
  const float* Whh1 = (const float*)d_in[7];
  const float* bih1 = (const float*)d_in[8];
  const float* bhh1 = (const float*)d_in[9];
  const float* fcW = (const float*)d_in[10];
  const float* fcb = (const float*)d_in[11];

  u32* hsl = (u32*)d_ws;  // 2 layers x 4 slots x 64 x 512 u32 = 1 MB

  hipMemsetAsync(hsl, 0, (size_t)2 * 4 * 64 * 512 * 4, stream);
  hipLaunchKernelGGL(k_rnn, dim3(64), dim3(256), 0, stream, x, emb, Wih0, Whh0,
                     bih0, bhh0, Wih1, Whh1, bih1, bhh1, hsl);
  // final h1 = step 512 -> layer1 slot (512&3)==0
  hipLaunchKernelGGL(k_fc, dim3(1), dim3(512), 0, stream,
                     hsl + (size_t)4 * 64 * 512, fcW, fcb, (float*)d_out);
}

// Round 7
// 2355.468 us; speedup vs baseline: 1.1877x; 1.1877x over previous
//
#include <hip/hip_runtime.h>
#include <stdint.h>

// RNNTextClassifier: B=64, S=512, E=H=512, NCLS=8
// Round 10: R8 base (proven 2073us) + per-wave DIRECT-to-register H poll.
// R9 post-mortem: restructure regressed 35% (8-way LDS write conflicts
// 6.3e7, 4 waves only, doubled staging VALU). The real cost is the H-path
// LDS round-trip + cross-wave B2 coupling, so R10 removes exactly that:
// each wave polls its OWN MFMA A-fragment words (lane(r16,kg) of wave kq:
// row bg*16+r16, cols kq*128+kt*32+kg*8) straight into VGPRs, builds
// ahi/alo via hipack/lopack in-register, MFMAs immediately. Deletes
// s_Hhi/s_Hlo staging, B2, and 12 b128 frag reads. Poll loops stay
// self-contained (R7 hazard lesson: no inline-asm load lives across a
// barrier). bp check folded into every wave's spin (lane<8); publishes
// remain gated by B3. in0 path / s_part reduce / finals / protocol
// byte-identical to R8. 2 barriers/step instead of 3.
// Ring: hsl[layer][slot=s&3][row 0..63][col 0..511] u32; tag = s&7.
// ws: hsl 1MB at offset 0 (memset to 0 each launch).

#define BB 64
#define SS 512
#define HH 512

typedef short bf16x8 __attribute__((ext_vector_type(8)));
typedef float f32x4 __attribute__((ext_vector_type(4)));
typedef int i32x4 __attribute__((ext_vector_type(4)));
typedef unsigned int u32;
typedef u32 u32x2 __attribute__((ext_vector_type(2)));

__device__ __forceinline__ unsigned short f2bf(float f) {
  uint32_t u = __builtin_bit_cast(uint32_t, f);
  u += 0x7FFFu + ((u >> 16) & 1u);
  return (unsigned short)(u >> 16);
}
__device__ __forceinline__ float bf2f(unsigned short h) {
  uint32_t u = ((uint32_t)h) << 16;
  return __builtin_bit_cast(float, u);
}
__device__ __forceinline__ int pack2(unsigned short a, unsigned short b) {
  return (int)(unsigned int)a | ((int)(unsigned int)b << 16);
}
// pack hi halves of two tagged words (a -> low bf16, b -> high bf16)
__device__ __forceinline__ u32 hipack(u32 a, u32 b) {
  return (a >> 16) | (b & 0xFFFF0000u);
}
// pack lo halves (tag bits stripped)
__device__ __forceinline__ u32 lopack(u32 a, u32 b) {
  return (a & 0xFFF8u) | ((b & 0xFFF8u) << 16);
}
__device__ __forceinline__ bool tag4(i32x4 v, u32 t) {
  u32 m = (((u32)v[0] ^ t) | ((u32)v[1] ^ t) | ((u32)v[2] ^ t) | ((u32)v[3] ^ t)) & 7u;
  return m == 0u;
}
// fast tanh: t = sign(v)*(1-e)/(1+e), e = exp(-2|v|). |err| ~1e-7.
__device__ __forceinline__ float fast_tanh(float v) {
  float a = __builtin_fabsf(v);
  float e = __expf(-2.0f * a);
  float t = (1.0f - e) / (1.0f + e);
  return __builtin_copysignf(t, v);
}

// device-coherent (UC) loads/stores: bypass non-common caches
#define UC_LOAD4(dst, ptr) \
  asm volatile("global_load_dwordx4 %0, %1, off sc0 sc1" : "=v"(dst) : "v"(ptr))
#define UC_LOAD1(dst, ptr) \
  asm volatile("global_load_dword %0, %1, off sc0 sc1" : "=v"(dst) : "v"(ptr))
#define UC_STORE2(ptr, v) \
  asm volatile("global_store_dwordx2 %0, %1, off sc0 sc1" ::"v"(ptr), "v"(v) : "memory")

__global__ __launch_bounds__(512, 2) void k_rnn(
    const int* __restrict__ x, const float* __restrict__ emb,
    const float* __restrict__ Wih0, const float* __restrict__ Whh0,
    const float* __restrict__ bih0, const float* __restrict__ bhh0,
    const float* __restrict__ Wih1, const float* __restrict__ Whh1,
    const float* __restrict__ bih1, const float* __restrict__ bhh1,
    u32* __restrict__ hsl) {
  const int tid = threadIdx.x;
  const int bid = blockIdx.x;
  const int layer = bid >> 5;  // 0 or 1
  const int lb = bid & 31;
  const int bg = lb >> 3;  // batch group (16 rows)
  const int c = lb & 7;    // hidden slice (64 dims)
  const int wid = tid >> 6;
  const int lane = tid & 63;
  const int kq = wid >> 1;  // K-quarter
  const int nh = wid & 1;   // N-half (32 cols)
  const int r16 = lane & 15, kg = lane >> 4;

  __shared__ __align__(16) unsigned short s_in0[16 * 512];
  __shared__ __align__(16) float s_part[4 * 16 * 64];

  const float* Wih = layer ? Wih1 : Wih0;
  const float* Whh = layer ? Whh1 : Whh0;
  const float* bi = layer ? bih1 : bih0;
  const float* bh = layer ? bhh1 : bhh0;

  // ---- one-time: W fragments into VGPRs ----
  bf16x8 wih[2][4], whhh[2][4], whhl[2][4];
  {
#pragma unroll
    for (int nt = 0; nt < 2; ++nt) {
#pragma unroll
      for (int kt = 0; kt < 4; ++kt) {
        int row = c * 64 + nh * 32 + nt * 16 + r16;
        int k0 = kq * 128 + kt * 32 + kg * 8;
        const float* p = Wih + row * 512 + k0;
        bf16x8 v;
#pragma unroll
        for (int j = 0; j < 8; ++j) v[j] = (short)f2bf(p[j]);
        wih[nt][kt] = v;
        const float* q = Whh + row * 512 + k0;
        bf16x8 vh, vl;
#pragma unroll
        for (int j = 0; j < 8; ++j) {
          float f = q[j];
          unsigned short h = f2bf(f);
          vh[j] = (short)h;
          vl[j] = (short)f2bf(f - bf2f(h));
        }
        whhh[nt][kt] = vh;
        whhl[nt][kt] = vl;
      }
    }
  }
  float biasv0, biasv1;
  {
    int na = (tid & 31) * 2;
    biasv0 = bi[c * 64 + na] + bh[c * 64 + na];
    biasv1 = bi[c * 64 + na + 1] + bh[c * 64 + na + 1];
  }

  const int r_st = tid >> 5;  // staging row 0..15
  const int ch = tid & 31;    // 16-element chunk of 512

  // prefetch in0 for step 1 (layer0: emb gather t=0)
  float4 pf0, pf1, pf2, pf3;
  if (layer == 0) {
    int rid = x[(bg * 16 + r_st) * SS + 0];
    const float4* ep = (const float4*)(emb + (size_t)rid * 512 + ch * 16);
    pf0 = ep[0]; pf1 = ep[1]; pf2 = ep[2]; pf3 = ep[3];
  }

  for (int s = 1; s <= SS; ++s) {
    const u32 exp_h = (u32)((s - 1) & 7);

    // ============ pre-poll phase: h-independent work ============
    if (layer == 0) {
      // stage in0 from prefetched emb f32 (swizzled LDS)
      i32x4 v0, v1;
      v0[0] = pack2(f2bf(pf0.x), f2bf(pf0.y));
      v0[1] = pack2(f2bf(pf0.z), f2bf(pf0.w));
      v0[2] = pack2(f2bf(pf1.x), f2bf(pf1.y));
      v0[3] = pack2(f2bf(pf1.z), f2bf(pf1.w));
      v1[0] = pack2(f2bf(pf2.x), f2bf(pf2.y));
      v1[1] = pack2(f2bf(pf2.z), f2bf(pf2.w));
      v1[2] = pack2(f2bf(pf3.x), f2bf(pf3.y));
      v1[3] = pack2(f2bf(pf3.z), f2bf(pf3.w));
      *(i32x4*)(s_in0 + r_st * 512 + (((2 * ch) ^ (r_st & 7)) << 3)) = v0;
      *(i32x4*)(s_in0 + r_st * 512 + (((2 * ch + 1) ^ (r_st & 7)) << 3)) = v1;
      // issue emb prefetch for s+1 (plain cached loads; hide under polls)
      if (s < SS) {
        int rid = x[(bg * 16 + r_st) * SS + s];
        const float4* ep = (const float4*)(emb + (size_t)rid * 512 + ch * 16);
        pf0 = ep[0]; pf1 = ep[1]; pf2 = ep[2]; pf3 = ep[3];
      }
    } else {
      // layer1: poll in0 = out0[s] (self-contained spin, proven shape)
      i32x4 i0 = {0, 0, 0, 0}, i1 = {0, 0, 0, 0}, i2 = {0, 0, 0, 0}, i3 = {0, 0, 0, 0};
      const u32 exp_i = (u32)(s & 7);
      const u32* pi =
          hsl + (((size_t)(s & 3)) * 64 + bg * 16 + r_st) * 512 + ch * 16;
      while (true) {
        UC_LOAD4(i0, pi);
        UC_LOAD4(i1, pi + 4);
        UC_LOAD4(i2, pi + 8);
        UC_LOAD4(i3, pi + 12);
        asm volatile("s_waitcnt vmcnt(0)"
                     : "+v"(i0), "+v"(i1), "+v"(i2), "+v"(i3)::"memory");
        bool ok = tag4(i0, exp_i) && tag4(i1, exp_i) && tag4(i2, exp_i) &&
                  tag4(i3, exp_i);
        if (__all(ok)) break;
      }
      // stage in0 (hi halves only) into swizzled LDS
      i32x4 A0 = {(int)hipack(i0[0], i0[1]), (int)hipack(i0[2], i0[3]),
                  (int)hipack(i1[0], i1[1]), (int)hipack(i1[2], i1[3])};
      i32x4 A1 = {(int)hipack(i2[0], i2[1]), (int)hipack(i2[2], i2[3]),
                  (int)hipack(i3[0], i3[1]), (int)hipack(i3[2], i3[3])};
      *(i32x4*)(s_in0 + r_st * 512 + (((2 * ch) ^ (r_st & 7)) << 3)) = A0;
      *(i32x4*)(s_in0 + r_st * 512 + (((2 * ch + 1) ^ (r_st & 7)) << 3)) = A1;
    }
    __syncthreads();  // B1: s_in0 staged

    // ---- in0 MFMAs (h-independent: hide under producer publish) ----
    f32x4 acc0 = {0.f, 0.f, 0.f, 0.f};
    f32x4 acc1 = {0.f, 0.f, 0.f, 0.f};
#pragma unroll
    for (int kt = 0; kt < 4; ++kt) {
      int k8 = kq * 16 + kt * 4 + kg;
      bf16x8 ain = __builtin_bit_cast(
          bf16x8, *(const i32x4*)(s_in0 + r16 * 512 + ((k8 ^ (r16 & 7)) << 3)));
      acc0 = __builtin_amdgcn_mfma_f32_16x16x32_bf16(ain, wih[0][kt], acc0, 0, 0, 0);
      acc1 = __builtin_amdgcn_mfma_f32_16x16x32_bf16(ain, wih[1][kt], acc1, 0, 0, 0);
    }

    // ============ H poll: per-wave direct-to-register (no LDS, no B2) ====
    if (s > 1) {
      // lane (r16,kg) of wave kq needs row bg*16+r16, cols kq*128+kt*32+kg*8
      i32x4 w0 = {0, 0, 0, 0}, w1 = {0, 0, 0, 0}, w2 = {0, 0, 0, 0}, w3 = {0, 0, 0, 0};
      i32x4 w4 = {0, 0, 0, 0}, w5 = {0, 0, 0, 0}, w6 = {0, 0, 0, 0}, w7 = {0, 0, 0, 0};
      const u32* phw = hsl +
          (((size_t)layer * 4 + ((s - 1) & 3)) * 64 + bg * 16 + r16) * 512 +
          kq * 128 + kg * 8;
      if (layer == 0) {
        const bool need_bp = (s > 4) && (lane < 8);
        const u32 exp_bp = (u32)((s - 4) & 7);
        const u32* pbp = hsl + ((size_t)(4 + ((s - 4) & 3)) * 64 + bg * 16) * 512 +
                         (lane < 8 ? lane * 64 : 0);
        while (true) {
          u32 bpw = 0;
          UC_LOAD4(w0, phw);
          UC_LOAD4(w1, phw + 4);
          UC_LOAD4(w2, phw + 32);
          UC_LOAD4(w3, phw + 36);
          UC_LOAD4(w4, phw + 64);
          UC_LOAD4(w5, phw + 68);
          UC_LOAD4(w6, phw + 96);
          UC_LOAD4(w7, phw + 100);
          UC_LOAD1(bpw, pbp);
          asm volatile("s_waitcnt vmcnt(0)"
                       : "+v"(w0), "+v"(w1), "+v"(w2), "+v"(w3), "+v"(w4), "+v"(w5),
                         "+v"(w6), "+v"(w7), "+v"(bpw)::"memory");
          bool ok = tag4(w0, exp_h) && tag4(w1, exp_h) && tag4(w2, exp_h) &&
                    tag4(w3, exp_h) && tag4(w4, exp_h) && tag4(w5, exp_h) &&
                    tag4(w6, exp_h) && tag4(w7, exp_h) &&
                    (!need_bp || ((bpw & 7u) == exp_bp));
          if (__all(ok)) break;
        }
      } else {
        while (true) {
          UC_LOAD4(w0, phw);
          UC_LOAD4(w1, phw + 4);
          UC_LOAD4(w2, phw + 32);
          UC_LOAD4(w3, phw + 36);
          UC_LOAD4(w4, phw + 64);
          UC_LOAD4(w5, phw + 68);
          UC_LOAD4(w6, phw + 96);
          UC_LOAD4(w7, phw + 100);
          asm volatile("s_waitcnt vmcnt(0)"
                       : "+v"(w0), "+v"(w1), "+v"(w2), "+v"(w3), "+v"(w4), "+v"(w5),
                         "+v"(w6), "+v"(w7)::"memory");
          bool ok = tag4(w0, exp_h) && tag4(w1, exp_h) && tag4(w2, exp_h) &&
                    tag4(w3, exp_h) && tag4(w4, exp_h) && tag4(w5, exp_h) &&
                    tag4(w6, exp_h) && tag4(w7, exp_h);
          if (__all(ok)) break;
        }
      }
      // build A-fragments in-register (hi / lo), then MFMA immediately
      bf16x8 ahi[4], alo[4];
      {
        i32x4 t;
        t[0] = (int)hipack(w0[0], w0[1]); t[1] = (int)hipack(w0[2], w0[3]);
        t[2] = (int)hipack(w1[0], w1[1]); t[3] = (int)hipack(w1[2], w1[3]);
        ahi[0] = __builtin_bit_cast(bf16x8, t);
        t[0] = (int)hipack(w2[0], w2[1]); t[1] = (int)hipack(w2[2], w2[3]);
        t[2] = (int)hipack(w3[0], w3[1]); t[3] = (int)hipack(w3[2], w3[3]);
        ahi[1] = __builtin_bit_cast(bf16x8, t);
        t[0] = (int)hipack(w4[0], w4[1]); t[1] = (int)hipack(w4[2], w4[3]);
        t[2] = (int)hipack(w5[0], w5[1]); t[3] = (int)hipack(w5[2], w5[3]);
        ahi[2] = __builtin_bit_cast(bf16x8, t);
        t[0] = (int)hipack(w6[0], w6[1]); t[1] = (int)hipack(w6[2], w6[3]);
        t[2] = (int)hipack(w7[0], w7[1]); t[3] = (int)hipack(w7[2], w7[3]);
        ahi[3] = __builtin_bit_cast(bf16x8, t);
        t[0] = (int)lopack(w0[0], w0[1]); t[1] = (int)lopack(w0[2], w0[3]);
        t[2] = (int)lopack(w1[0], w1[1]); t[3] = (int)lopack(w1[2], w1[3]);
        alo[0] = __builtin_bit_cast(bf16x8, t);
        t[0] = (int)lopack(w2[0], w2[1]); t[1] = (int)lopack(w2[2], w2[3]);
        t[2] = (int)lopack(w3[0], w3[1]); t[3] = (int)lopack(w3[2], w3[3]);
        alo[1] = __builtin_bit_cast(bf16x8, t);
        t[0] = (int)lopack(w4[0], w4[1]); t[1] = (int)lopack(w4[2], w4[3]);
        t[2] = (int)lopack(w5[0], w5[1]); t[3] = (int)lopack(w5[2], w5[3]);
        alo[2] = __builtin_bit_cast(bf16x8, t);
        t[0] = (int)lopack(w6[0], w6[1]); t[1] = (int)lopack(w6[2], w6[3]);
        t[2] = (int)lopack(w7[0], w7[1]); t[3] = (int)lopack(w7[2], w7[3]);
        alo[3] = __builtin_bit_cast(bf16x8, t);
      }
      // H MFMAs: 3-term hi/lo, straight from registers
#pragma unroll
      for (int kt = 0; kt < 4; ++kt) {
        acc0 = __builtin_amdgcn_mfma_f32_16x16x32_bf16(ahi[kt], whhh[0][kt], acc0, 0, 0, 0);
        acc0 = __builtin_amdgcn_mfma_f32_16x16x32_bf16(ahi[kt], whhl[0][kt], acc0, 0, 0, 0);
        acc0 = __builtin_amdgcn_mfma_f32_16x16x32_bf16(alo[kt], whhh[0][kt], acc0, 0, 0, 0);
        acc1 = __builtin_amdgcn_mfma_f32_16x16x32_bf16(ahi[kt], whhh[1][kt], acc1, 0, 0, 0);
        acc1 = __builtin_amdgcn_mfma_f32_16x16x32_bf16(ahi[kt], whhl[1][kt], acc1, 0, 0, 0);
        acc1 = __builtin_amdgcn_mfma_f32_16x16x32_bf16(alo[kt], whhh[1][kt], acc1, 0, 0, 0);
      }
    }

    // ---- partial-sum write ----
    {
#pragma unroll
      for (int j = 0; j < 4; ++j) {
        int m = kg * 4 + j;
        int xr = (m >> 2) & 3;
        int n0i = nh * 32 + 0 * 16 + r16;
        int n1i = nh * 32 + 1 * 16 + r16;
        s_part[kq * 1024 + m * 64 + (n0i ^ (xr << 4))] = acc0[j];
        s_part[kq * 1024 + m * 64 + (n1i ^ (xr << 4))] = acc1[j];
      }
    }
    __syncthreads();  // B3

    // ---- finals: reduce, bias, fast-tanh, pack word (hi|lo|tag), publish ----
    {
      int m = tid >> 5, na = (tid & 31) * 2;
      int xr = (m >> 2) & 3;
      float v0 = biasv0, v1 = biasv1;
#pragma unroll
      for (int q2 = 0; q2 < 4; ++q2) {
        const float2* sp =
            (const float2*)(s_part + q2 * 1024 + m * 64 + (na ^ (xr << 4)));
        float2 t = *sp;
        v0 += t.x;
        v1 += t.y;
      }
      v0 = fast_tanh(v0);
      v1 = fast_tanh(v1);
      unsigned short a0 = f2bf(v0), a1 = f2bf(v1);
      unsigned short b0 = f2bf(v0 - bf2f(a0)), b1 = f2bf(v1 - bf2f(a1));
      u32 tag = (u32)(s & 7);
      u32x2 wv;
      wv[0] = ((u32)a0 << 16) | ((u32)b0 & 0xFFF8u) | tag;
      wv[1] = ((u32)a1 << 16) | ((u32)b1 & 0xFFF8u) | tag;
      u32* dst = hsl + (((size_t)layer * 4 + (s & 3)) * 64 + bg * 16 + m) * 512 +
                 c * 64 + na;
      UC_STORE2(dst, wv);
    }
    // no drain, no flag: consumers detect via embedded tags
  }
}

__global__ void k_fc(const u32* __restrict__ h1w, const float* __restrict__ fcW,
                     const float* __restrict__ fcb, float* __restrict__ out) {
  int i = threadIdx.x;  // 512 = 64 batch x 8 classes
  int b = i >> 3, cc = i & 7;
  float acc = fcb[cc];
  const u32* ph = h1w + b * 512;
  const float* pw = fcW + cc * 512;
  for (int k = 0; k < 512; k += 4) {
    int4 w4 = *(const int4*)(ph + k);
    float4 wv = *(const float4*)(pw + k);
    acc += (bf2f((unsigned short)((u32)w4.x >> 16)) +
            bf2f((unsigned short)((u32)w4.x & 0xFFF8u))) * wv.x;
    acc += (bf2f((unsigned short)((u32)w4.y >> 16)) +
            bf2f((unsigned short)((u32)w4.y & 0xFFF8u))) * wv.y;
    acc += (bf2f((unsigned short)((u32)w4.z >> 16)) +
            bf2f((unsigned short)((u32)w4.z & 0xFFF8u))) * wv.z;
    acc += (bf2f((unsigned short)((u32)w4.w >> 16)) +
            bf2f((unsigned short)((u32)w4.w & 0xFFF8u))) * wv.w;
  }
  out[b * 8 + cc] = acc;
}

extern "C" void kernel_launch(void* const* d_in, const int* in_sizes, int n_in,
                              void* d_out, int out_size, void* d_ws, size_t ws_size,
                              hipStream_t stream) {
  const int* x = (const int*)d_in[0];
  const float* emb = (const float*)d_in[1];
  const float* Wih0 = (const float*)d_in[2];
  const float* Whh0 = (const float*)d_in[3];
  const float* bih0 = (const float*)d_in[4];
  const float* bhh0 = (const float*)d_in[5];
  const float* Wih1 = (const float*)d_in[6];
  const float* Whh1 = (const float*)d_in[7];
  const float* bih1 = (const float*)d_in[8];
  const float* bhh1 = (const float*)d_in[9];
  const float* fcW = (const float*)d_in[10];
  const float* fcb = (const float*)d_in[11];

  u32* hsl = (u32*)d_ws;  // 2 layers x 4 slots x 64 x 512 u32 = 1 MB

  hipMemsetAsync(hsl, 0, (size_t)2 * 4 * 64 * 512 * 4, stream);
  hipLaunchKernelGGL(k_rnn, dim3(64), dim3(512), 0, stream, x, emb, Wih0, Whh0,
                     bih0, bhh0, Wih1, Whh1, bih1, bhh1, hsl);
  // final h1 = step 512 -> layer1 slot (512&3)==0
  hipLaunchKernelGGL(k_fc, dim3(1), dim3(512), 0, stream,
                     hsl + (size_t)4 * 64 * 512, fcW, fcb, (float*)d_out);
}

// Round 8
// 2084.503 us; speedup vs baseline: 1.3421x; 1.1300x over previous
//
#include <hip/hip_runtime.h>
#include <stdint.h>

// RNNTextClassifier: B=64, S=512, E=H=512, NCLS=8
// Round 11: R8 base (proven 2073us) + barrier-drain elimination.
// R9/R10 lesson: do NOT restructure staging (duplicated poll traffic /
// LDS conflicts cost more than barriers save). R11 keeps R8's structure
// byte-for-byte and removes hidden serialization:
//  1) __syncthreads -> s_waitcnt lgkmcnt(0) + s_barrier (B1/B2/B3 protect
//     LDS only). Stops force-draining vmcnt at barriers: the emb prefetch
//     and the fire-and-forget publish store stay in flight (m97: hipcc
//     emits vmcnt(0) drain before s_barrier; m201 pattern for raw bars).
//  2) emb prefetch issue moved AFTER in0 MFMAs, right before the H poll:
//     its HBM latency hides under the poll's first MALL round trip.
//  3) H MFMA chain split 16-deep -> 4 chains of 4 per n-half
//     (in0 / ahi*whhh / ahi*whhl / alo*whhh), summed before s_part.
// Protocol identical: tagged-data device-scope polls, ring slot=s&3,
// tag=s&7, layer0 bp-polls layer1 progress, self-contained spin loops.
// ws: hsl 1MB at offset 0 (memset to 0 each launch).

#define BB 64
#define SS 512
#define HH 512

typedef short bf16x8 __attribute__((ext_vector_type(8)));
typedef float f32x4 __attribute__((ext_vector_type(4)));
typedef int i32x4 __attribute__((ext_vector_type(4)));
typedef unsigned int u32;
typedef u32 u32x2 __attribute__((ext_vector_type(2)));

__device__ __forceinline__ unsigned short f2bf(float f) {
  uint32_t u = __builtin_bit_cast(uint32_t, f);
  u += 0x7FFFu + ((u >> 16) & 1u);
  return (unsigned short)(u >> 16);
}
__device__ __forceinline__ float bf2f(unsigned short h) {
  uint32_t u = ((uint32_t)h) << 16;
  return __builtin_bit_cast(float, u);
}
__device__ __forceinline__ int pack2(unsigned short a, unsigned short b) {
  return (int)(unsigned int)a | ((int)(unsigned int)b << 16);
}
// pack hi halves of two tagged words (a -> low bf16, b -> high bf16)
__device__ __forceinline__ u32 hipack(u32 a, u32 b) {
  return (a >> 16) | (b & 0xFFFF0000u);
}
// pack lo halves (tag bits stripped)
__device__ __forceinline__ u32 lopack(u32 a, u32 b) {
  return (a & 0xFFF8u) | ((b & 0xFFF8u) << 16);
}
__device__ __forceinline__ bool tag4(i32x4 v, u32 t) {
  u32 m = (((u32)v[0] ^ t) | ((u32)v[1] ^ t) | ((u32)v[2] ^ t) | ((u32)v[3] ^ t)) & 7u;
  return m == 0u;
}
// fast tanh: t = sign(v)*(1-e)/(1+e), e = exp(-2|v|). |err| ~1e-7.
__device__ __forceinline__ float fast_tanh(float v) {
  float a = __builtin_fabsf(v);
  float e = __expf(-2.0f * a);
  float t = (1.0f - e) / (1.0f + e);
  return __builtin_copysignf(t, v);
}

// LDS-only barrier: no vmcnt drain (B1/B2/B3 protect LDS staging only).
#define BAR_LDS()                                            \
  do {                                                       \
    asm volatile("s_waitcnt lgkmcnt(0)" ::: "memory");       \
    __builtin_amdgcn_s_barrier();                            \
  } while (0)

// device-coherent (UC) loads/stores: bypass non-common caches
#define UC_LOAD4(dst, ptr) \
  asm volatile("global_load_dwordx4 %0, %1, off sc0 sc1" : "=v"(dst) : "v"(ptr))
#define UC_LOAD1(dst, ptr) \
  asm volatile("global_load_dword %0, %1, off sc0 sc1" : "=v"(dst) : "v"(ptr))
#define UC_STORE2(ptr, v) \
  asm volatile("global_store_dwordx2 %0, %1, off sc0 sc1" ::"v"(ptr), "v"(v) : "memory")

__global__ __launch_bounds__(512, 2) void k_rnn(
    const int* __restrict__ x, const float* __restrict__ emb,
    const float* __restrict__ Wih0, const float* __restrict__ Whh0,
    const float* __restrict__ bih0, const float* __restrict__ bhh0,
    const float* __restrict__ Wih1, const float* __restrict__ Whh1,
    const float* __restrict__ bih1, const float* __restrict__ bhh1,
    u32* __restrict__ hsl) {
  const int tid = threadIdx.x;
  const int bid = blockIdx.x;
  const int layer = bid >> 5;  // 0 or 1
  const int lb = bid & 31;
  const int bg = lb >> 3;  // batch group (16 rows)
  const int c = lb & 7;    // hidden slice (64 dims)
  const int wid = tid >> 6;
  const int lane = tid & 63;
  const int kq = wid >> 1;  // K-quarter
  const int nh = wid & 1;   // N-half (32 cols)
  const int r16 = lane & 15, kg = lane >> 4;

  __shared__ __align__(16) unsigned short s_in0[16 * 512];
  __shared__ __align__(16) unsigned short s_Hhi[16 * 512];
  __shared__ __align__(16) unsigned short s_Hlo[16 * 512];
  __shared__ __align__(16) float s_part[4 * 16 * 64];

  const float* Wih = layer ? Wih1 : Wih0;
  const float* Whh = layer ? Whh1 : Whh0;
  const float* bi = layer ? bih1 : bih0;
  const float* bh = layer ? bhh1 : bhh0;

  // ---- one-time: W fragments into VGPRs ----
  bf16x8 wih[2][4], whhh[2][4], whhl[2][4];
  {
#pragma unroll
    for (int nt = 0; nt < 2; ++nt) {
#pragma unroll
      for (int kt = 0; kt < 4; ++kt) {
        int row = c * 64 + nh * 32 + nt * 16 + r16;
        int k0 = kq * 128 + kt * 32 + kg * 8;
        const float* p = Wih + row * 512 + k0;
        bf16x8 v;
#pragma unroll
        for (int j = 0; j < 8; ++j) v[j] = (short)f2bf(p[j]);
        wih[nt][kt] = v;
        const float* q = Whh + row * 512 + k0;
        bf16x8 vh, vl;
#pragma unroll
        for (int j = 0; j < 8; ++j) {
          float f = q[j];
          unsigned short h = f2bf(f);
          vh[j] = (short)h;
          vl[j] = (short)f2bf(f - bf2f(h));
        }
        whhh[nt][kt] = vh;
        whhl[nt][kt] = vl;
      }
    }
  }
  float biasv0, biasv1;
  {
    int na = (tid & 31) * 2;
    biasv0 = bi[c * 64 + na] + bh[c * 64 + na];
    biasv1 = bi[c * 64 + na + 1] + bh[c * 64 + na + 1];
  }

  const int r_st = tid >> 5;  // staging row 0..15
  const int ch = tid & 31;    // 16-element chunk of 512

  // prefetch in0 for step 1 (layer0: emb gather t=0)
  float4 pf0, pf1, pf2, pf3;
  if (layer == 0) {
    int rid = x[(bg * 16 + r_st) * SS + 0];
    const float4* ep = (const float4*)(emb + (size_t)rid * 512 + ch * 16);
    pf0 = ep[0]; pf1 = ep[1]; pf2 = ep[2]; pf3 = ep[3];
  }

  for (int s = 1; s <= SS; ++s) {
    const u32 exp_h = (u32)((s - 1) & 7);
    const u32* ph = hsl +
        (((size_t)layer * 4 + ((s - 1) & 3)) * 64 + bg * 16 + r_st) * 512 + ch * 16;

    // next emb row index (plain load; stays in flight across B1 — raw
    // barrier does not drain vmcnt)
    int nrid = 0;
    if (layer == 0 && s < SS) nrid = x[(bg * 16 + r_st) * SS + s];

    // ============ pre-poll phase: h-independent work ============
    if (layer == 0) {
      // stage in0 from prefetched emb f32 (swizzled LDS)
      i32x4 v0, v1;
      v0[0] = pack2(f2bf(pf0.x), f2bf(pf0.y));
      v0[1] = pack2(f2bf(pf0.z), f2bf(pf0.w));
      v0[2] = pack2(f2bf(pf1.x), f2bf(pf1.y));
      v0[3] = pack2(f2bf(pf1.z), f2bf(pf1.w));
      v1[0] = pack2(f2bf(pf2.x), f2bf(pf2.y));
      v1[1] = pack2(f2bf(pf2.z), f2bf(pf2.w));
      v1[2] = pack2(f2bf(pf3.x), f2bf(pf3.y));
      v1[3] = pack2(f2bf(pf3.z), f2bf(pf3.w));
      *(i32x4*)(s_in0 + r_st * 512 + (((2 * ch) ^ (r_st & 7)) << 3)) = v0;
      *(i32x4*)(s_in0 + r_st * 512 + (((2 * ch + 1) ^ (r_st & 7)) << 3)) = v1;
    } else {
      // layer1: poll in0 = out0[s] (self-contained spin, proven shape)
      i32x4 i0 = {0, 0, 0, 0}, i1 = {0, 0, 0, 0}, i2 = {0, 0, 0, 0}, i3 = {0, 0, 0, 0};
      const u32 exp_i = (u32)(s & 7);
      const u32* pi =
          hsl + (((size_t)(s & 3)) * 64 + bg * 16 + r_st) * 512 + ch * 16;
      while (true) {
        UC_LOAD4(i0, pi);
        UC_LOAD4(i1, pi + 4);
        UC_LOAD4(i2, pi + 8);
        UC_LOAD4(i3, pi + 12);
        asm volatile("s_waitcnt vmcnt(0)"
                     : "+v"(i0), "+v"(i1), "+v"(i2), "+v"(i3)::"memory");
        bool ok = tag4(i0, exp_i) && tag4(i1, exp_i) && tag4(i2, exp_i) &&
                  tag4(i3, exp_i);
        if (__all(ok)) break;
      }
      // stage in0 (hi halves only) into swizzled LDS
      i32x4 A0 = {(int)hipack(i0[0], i0[1]), (int)hipack(i0[2], i0[3]),
                  (int)hipack(i1[0], i1[1]), (int)hipack(i1[2], i1[3])};
      i32x4 A1 = {(int)hipack(i2[0], i2[1]), (int)hipack(i2[2], i2[3]),
                  (int)hipack(i3[0], i3[1]), (int)hipack(i3[2], i3[3])};
      *(i32x4*)(s_in0 + r_st * 512 + (((2 * ch) ^ (r_st & 7)) << 3)) = A0;
      *(i32x4*)(s_in0 + r_st * 512 + (((2 * ch + 1) ^ (r_st & 7)) << 3)) = A1;
    }
    BAR_LDS();  // B1: s_in0 staged (LDS-only; vmem stays in flight)

    // ---- in0 MFMAs (h-independent: hide under producer publish) ----
    f32x4 a0i = {0.f, 0.f, 0.f, 0.f};
    f32x4 a1i = {0.f, 0.f, 0.f, 0.f};
#pragma unroll
    for (int kt = 0; kt < 4; ++kt) {
      int k8 = kq * 16 + kt * 4 + kg;
      bf16x8 ain = __builtin_bit_cast(
          bf16x8, *(const i32x4*)(s_in0 + r16 * 512 + ((k8 ^ (r16 & 7)) << 3)));
      a0i = __builtin_amdgcn_mfma_f32_16x16x32_bf16(ain, wih[0][kt], a0i, 0, 0, 0);
      a1i = __builtin_amdgcn_mfma_f32_16x16x32_bf16(ain, wih[1][kt], a1i, 0, 0, 0);
    }

    // ---- issue emb prefetch for s+1: hides under the H-poll MALL RT ----
    if (layer == 0 && s < SS) {
      const float4* ep = (const float4*)(emb + (size_t)nrid * 512 + ch * 16);
      pf0 = ep[0]; pf1 = ep[1]; pf2 = ep[2]; pf3 = ep[3];
    }

    // ============ H poll (self-contained) + stage ============
    f32x4 a0hh = {0.f, 0.f, 0.f, 0.f}, a0hl = {0.f, 0.f, 0.f, 0.f},
          a0lh = {0.f, 0.f, 0.f, 0.f};
    f32x4 a1hh = {0.f, 0.f, 0.f, 0.f}, a1hl = {0.f, 0.f, 0.f, 0.f},
          a1lh = {0.f, 0.f, 0.f, 0.f};
    if (s > 1) {
      i32x4 h0 = {0, 0, 0, 0}, h1 = {0, 0, 0, 0}, h2 = {0, 0, 0, 0}, h3 = {0, 0, 0, 0};
      if (layer == 0) {
        const bool need_bp = (s > 4) && (tid < 8);
        const u32 exp_bp = (u32)((s - 4) & 7);
        const u32* pbp = hsl + ((size_t)(4 + ((s - 4) & 3)) * 64 + bg * 16) * 512 +
                         (tid < 8 ? tid * 64 : 0);
        while (true) {
          u32 bpw = 0;
          UC_LOAD4(h0, ph);
          UC_LOAD4(h1, ph + 4);
          UC_LOAD4(h2, ph + 8);
          UC_LOAD4(h3, ph + 12);
          UC_LOAD1(bpw, pbp);
          asm volatile("s_waitcnt vmcnt(0)"
                       : "+v"(h0), "+v"(h1), "+v"(h2), "+v"(h3), "+v"(bpw)::"memory");
          bool ok = tag4(h0, exp_h) && tag4(h1, exp_h) && tag4(h2, exp_h) &&
                    tag4(h3, exp_h) && (!need_bp || ((bpw & 7u) == exp_bp));
          if (__all(ok)) break;
        }
      } else {
        while (true) {
          UC_LOAD4(h0, ph);
          UC_LOAD4(h1, ph + 4);
          UC_LOAD4(h2, ph + 8);
          UC_LOAD4(h3, ph + 12);
          asm volatile("s_waitcnt vmcnt(0)"
                       : "+v"(h0), "+v"(h1), "+v"(h2), "+v"(h3)::"memory");
          bool ok = tag4(h0, exp_h) && tag4(h1, exp_h) && tag4(h2, exp_h) &&
                    tag4(h3, exp_h);
          if (__all(ok)) break;
        }
      }
      // stage H hi/lo (deinterleave tagged words)
      i32x4 A0 = {(int)hipack(h0[0], h0[1]), (int)hipack(h0[2], h0[3]),
                  (int)hipack(h1[0], h1[1]), (int)hipack(h1[2], h1[3])};
      i32x4 A1 = {(int)hipack(h2[0], h2[1]), (int)hipack(h2[2], h2[3]),
                  (int)hipack(h3[0], h3[1]), (int)hipack(h3[2], h3[3])};
      i32x4 B0 = {(int)lopack(h0[0], h0[1]), (int)lopack(h0[2], h0[3]),
                  (int)lopack(h1[0], h1[1]), (int)lopack(h1[2], h1[3])};
      i32x4 B1v = {(int)lopack(h2[0], h2[1]), (int)lopack(h2[2], h2[3]),
                   (int)lopack(h3[0], h3[1]), (int)lopack(h3[2], h3[3])};
      *(i32x4*)(s_Hhi + r_st * 512 + (((2 * ch) ^ (r_st & 7)) << 3)) = A0;
      *(i32x4*)(s_Hhi + r_st * 512 + (((2 * ch + 1) ^ (r_st & 7)) << 3)) = A1;
      *(i32x4*)(s_Hlo + r_st * 512 + (((2 * ch) ^ (r_st & 7)) << 3)) = B0;
      *(i32x4*)(s_Hlo + r_st * 512 + (((2 * ch + 1) ^ (r_st & 7)) << 3)) = B1v;
    }
    BAR_LDS();  // B2: s_H staged (LDS-only)

    // ---- H MFMAs: 3 independent 4-deep chains per n-half ----
    if (s > 1) {
#pragma unroll
      for (int kt = 0; kt < 4; ++kt) {
        int k8 = kq * 16 + kt * 4 + kg;
        bf16x8 ahi = __builtin_bit_cast(
            bf16x8, *(const i32x4*)(s_Hhi + r16 * 512 + ((k8 ^ (r16 & 7)) << 3)));
        bf16x8 alo = __builtin_bit_cast(
            bf16x8, *(const i32x4*)(s_Hlo + r16 * 512 + ((k8 ^ (r16 & 7)) << 3)));
        a0hh = __builtin_amdgcn_mfma_f32_16x16x32_bf16(ahi, whhh[0][kt], a0hh, 0, 0, 0);
        a0hl = __builtin_amdgcn_mfma_f32_16x16x32_bf16(ahi, whhl[0][kt], a0hl, 0, 0, 0);
        a0lh = __builtin_amdgcn_mfma_f32_16x16x32_bf16(alo, whhh[0][kt], a0lh, 0, 0, 0);
        a1hh = __builtin_amdgcn_mfma_f32_16x16x32_bf16(ahi, whhh[1][kt], a1hh, 0, 0, 0);
        a1hl = __builtin_amdgcn_mfma_f32_16x16x32_bf16(ahi, whhl[1][kt], a1hl, 0, 0, 0);
        a1lh = __builtin_amdgcn_mfma_f32_16x16x32_bf16(alo, whhh[1][kt], a1lh, 0, 0, 0);
      }
    }

    // ---- partial-sum write (sum the 4 chains first) ----
    {
      f32x4 acc0 = (a0i + a0hh) + (a0hl + a0lh);
      f32x4 acc1 = (a1i + a1hh) + (a1hl + a1lh);
#pragma unroll
      for (int j = 0; j < 4; ++j) {
        int m = kg * 4 + j;
        int xr = (m >> 2) & 3;
        int n0i = nh * 32 + 0 * 16 + r16;
        int n1i = nh * 32 + 1 * 16 + r16;
        s_part[kq * 1024 + m * 64 + (n0i ^ (xr << 4))] = acc0[j];
        s_part[kq * 1024 + m * 64 + (n1i ^ (xr << 4))] = acc1[j];
      }
    }
    BAR_LDS();  // B3: s_part staged (LDS-only)

    // ---- finals: reduce, bias, fast-tanh, pack word (hi|lo|tag), publish ----
    {
      int m = tid >> 5, na = (tid & 31) * 2;
      int xr = (m >> 2) & 3;
      float v0 = biasv0, v1 = biasv1;
#pragma unroll
      for (int q2 = 0; q2 < 4; ++q2) {
        const float2* sp =
            (const float2*)(s_part + q2 * 1024 + m * 64 + (na ^ (xr << 4)));
        float2 t = *sp;
        v0 += t.x;
        v1 += t.y;
      }
      v0 = fast_tanh(v0);
      v1 = fast_tanh(v1);
      unsigned short a0 = f2bf(v0), a1 = f2bf(v1);
      unsigned short b0 = f2bf(v0 - bf2f(a0)), b1 = f2bf(v1 - bf2f(a1));
      u32 tag = (u32)(s & 7);
      u32x2 wv;
      wv[0] = ((u32)a0 << 16) | ((u32)b0 & 0xFFF8u) | tag;
      wv[1] = ((u32)a1 << 16) | ((u32)b1 & 0xFFF8u) | tag;
      u32* dst = hsl + (((size_t)layer * 4 + (s & 3)) * 64 + bg * 16 + m) * 512 +
                 c * 64 + na;
      UC_STORE2(dst, wv);
    }
    // fire-and-forget publish; next barrier does NOT drain it (lgkm-only).
    // One extra LDS-only barrier so s_part (B3-consumed) can't be
    // overwritten by the next step's s_in0... different buffers — not
    // needed. s_part reuse is next step's B3, gated by B1/B2 anyway.
  }
}

__global__ void k_fc(const u32* __restrict__ h1w, const float* __restrict__ fcW,
                     const float* __restrict__ fcb, float* __restrict__ out) {
  int i = threadIdx.x;  // 512 = 64 batch x 8 classes
  int b = i >> 3, cc = i & 7;
  float acc = fcb[cc];
  const u32* ph = h1w + b * 512;
  const float* pw = fcW + cc * 512;
  for (int k = 0; k < 512; k += 4) {
    int4 w4 = *(const int4*)(ph + k);
    float4 wv = *(const float4*)(pw + k);
    acc += (bf2f((unsigned short)((u32)w4.x >> 16)) +
            bf2f((unsigned short)((u32)w4.x & 0xFFF8u))) * wv.x;
    acc += (bf2f((unsigned short)((u32)w4.y >> 16)) +
            bf2f((unsigned short)((u32)w4.y & 0xFFF8u))) * wv.y;
    acc += (bf2f((unsigned short)((u32)w4.z >> 16)) +
            bf2f((unsigned short)((u32)w4.z & 0xFFF8u))) * wv.z;
    acc += (bf2f((unsigned short)((u32)w4.w >> 16)) +
            bf2f((unsigned short)((u32)w4.w & 0xFFF8u))) * wv.w;
  }
  out[b * 8 + cc] = acc;
}

extern "C" void kernel_launch(void* const* d_in, const int* in_sizes, int n_in,
                              void* d_out, int out_size, void* d_ws, size_t ws_size,
                              hipStream_t stream) {
  const int* x = (const int*)d_in[0];
  const float* emb = (const float*)d_in[1];
  const float* Wih0 = (const float*)d_in[2];
  const float* Whh0 = (const float*)d_in[3];
  const float* bih0 = (const float*)d_in[4];
  const float* bhh0 = (const float*)d_in[5];
  const float* Wih1 = (const float*)d_in[6];
  const float* Whh1 = (const float*)d_in[7];
  const float* bih1 = (const float*)d_in[8];
  const float* bhh1 = (const float*)d_in[9];
  const float* fcW = (const float*)d_in[10];
  const float* fcb = (const float*)d_in[11];

  u32* hsl = (u32*)d_ws;  // 2 layers x 4 slots x 64 x 512 u32 = 1 MB

  hipMemsetAsync(hsl, 0, (size_t)2 * 4 * 64 * 512 * 4, stream);
  hipLaunchKernelGGL(k_rnn, dim3(64), dim3(512), 0, stream, x, emb, Wih0, Whh0,
                     bih0, bhh0, Wih1, Whh1, bih1, bhh1, hsl);
  // final h1 = step 512 -> layer1 slot (512&3)==0
  hipLaunchKernelGGL(k_fc, dim3(1), dim3(512), 0, stream,
                     hsl + (size_t)4 * 64 * 512, fcW, fcb, (float*)d_out);
}